// Round 1
// baseline (1159.041 us; speedup 1.0000x reference)
//
#include <hip/hip_runtime.h>
#include <math.h>

#define N_NODESC 100000
#define N_EDGESC 1600000
#define E_TOT    1700000   // incl. self loops
#define IN_CH    500
#define D1 64
#define H1C 8
#define D2 24
#define H2C 8

// ---------------- K1: xw1 = x @ W1 (fp32, 64x64 tile, 4x4/thread) ----------------
__global__ __launch_bounds__(256) void k_gemm1(const float* __restrict__ x,
                                               const float* __restrict__ W1,
                                               float* __restrict__ xw1) {
    __shared__ float xs[64 * 64];   // [kk][row]  (transposed x tile)
    __shared__ float wcs[64 * 64];  // [kk][col]
    const int t = threadIdx.x;
    const int rowBase = blockIdx.x * 64;
    const int tr = t >> 4;          // 0..15 -> rows 4tr..4tr+3
    const int tc = t & 15;          // 0..15 -> cols 4tc..4tc+3
    const int lr = t >> 2;          // 0..63 (row for x load)
    const int lq = t & 3;           // 0..3  (k-quarter for x load)

    float acc[4][4];
#pragma unroll
    for (int i = 0; i < 4; i++)
#pragma unroll
        for (int j = 0; j < 4; j++) acc[i][j] = 0.f;

    for (int k0 = 0; k0 < IN_CH; k0 += 64) {
        __syncthreads();
        // load x tile (transposed into LDS)
        {
            const int row = rowBase + lr;
#pragma unroll
            for (int i = 0; i < 4; i++) {
                const int kk = lq * 16 + i * 4;
                const int k = k0 + kk;
                float4 v = make_float4(0.f, 0.f, 0.f, 0.f);
                if (row < N_NODESC && k < IN_CH)
                    v = *(const float4*)(x + (long)row * IN_CH + k);
                xs[(kk + 0) * 64 + lr] = v.x;
                xs[(kk + 1) * 64 + lr] = v.y;
                xs[(kk + 2) * 64 + lr] = v.z;
                xs[(kk + 3) * 64 + lr] = v.w;
            }
        }
        // load W tile
        {
#pragma unroll
            for (int i = 0; i < 4; i++) {
                const int o = t * 16 + i * 4;
                float4 v = make_float4(0.f, 0.f, 0.f, 0.f);
                if (k0 + (o >> 6) < IN_CH)
                    v = *(const float4*)(W1 + k0 * 64 + o);
                *(float4*)(wcs + o) = v;
            }
        }
        __syncthreads();
#pragma unroll
        for (int kk = 0; kk < 64; kk++) {
            const float4 xv = *(const float4*)(xs + kk * 64 + tr * 4);
            const float4 wv = *(const float4*)(wcs + kk * 64 + tc * 4);
            acc[0][0] += xv.x * wv.x; acc[0][1] += xv.x * wv.y; acc[0][2] += xv.x * wv.z; acc[0][3] += xv.x * wv.w;
            acc[1][0] += xv.y * wv.x; acc[1][1] += xv.y * wv.y; acc[1][2] += xv.y * wv.z; acc[1][3] += xv.y * wv.w;
            acc[2][0] += xv.z * wv.x; acc[2][1] += xv.z * wv.y; acc[2][2] += xv.z * wv.z; acc[2][3] += xv.z * wv.w;
            acc[3][0] += xv.w * wv.x; acc[3][1] += xv.w * wv.y; acc[3][2] += xv.w * wv.z; acc[3][3] += xv.w * wv.w;
        }
    }
#pragma unroll
    for (int rr = 0; rr < 4; rr++) {
        const int row = rowBase + tr * 4 + rr;
        if (row < N_NODESC)
            *(float4*)(xw1 + (long)row * D1 + tc * 4) =
                make_float4(acc[rr][0], acc[rr][1], acc[rr][2], acc[rr][3]);
    }
}

// ---------------- K2: attention logit projections, layer 1 ----------------
__global__ __launch_bounds__(256) void k_al1(const float* __restrict__ xw1,
                                             const float* __restrict__ a1s,
                                             const float* __restrict__ a1d,
                                             float* __restrict__ al1s,
                                             float* __restrict__ al1d) {
    const int gid = blockIdx.x * 256 + threadIdx.x;
    if (gid >= N_NODESC * H1C) return;
    const int n = gid >> 3, h = gid & 7;
    const float4* p = (const float4*)(xw1 + (long)n * D1 + h * 8);
    const float4 v0 = p[0], v1 = p[1];
    const float4* as = (const float4*)(a1s + h * 8);
    const float4 s0 = as[0], s1 = as[1];
    const float4* ad = (const float4*)(a1d + h * 8);
    const float4 d0 = ad[0], d1 = ad[1];
    al1s[gid] = v0.x * s0.x + v0.y * s0.y + v0.z * s0.z + v0.w * s0.w +
                v1.x * s1.x + v1.y * s1.y + v1.z * s1.z + v1.w * s1.w;
    al1d[gid] = v0.x * d0.x + v0.y * d0.y + v0.z * d0.z + v0.w * d0.w +
                v1.x * d1.x + v1.y * d1.y + v1.z * d1.z + v1.w * d1.w;
}

// ---------------- K4: edge aggregation, layer 1 (64 lanes per edge) ----------------
__global__ __launch_bounds__(256) void k_edge1(const int* __restrict__ ei,
                                               const float* __restrict__ al1s,
                                               const float* __restrict__ al1d,
                                               const float* __restrict__ xw1,
                                               float* __restrict__ acc1,
                                               float* __restrict__ s1) {
    const long gid = (long)blockIdx.x * 256 + threadIdx.x;
    if (gid >= (long)E_TOT * 64) return;
    const int e = (int)(gid >> 6);
    const int lane = (int)gid & 63;
    const int h = lane >> 3;
    int s, d;
    if (e < N_EDGESC) { s = ei[e]; d = ei[N_EDGESC + e]; }
    else { s = d = e - N_EDGESC; }
    float ev = al1s[s * 8 + h] + al1d[d * 8 + h];
    ev = ev > 0.f ? ev : 0.2f * ev;
    const float ex = expf(ev);   // no max-subtraction: softmax shift-invariant, logits are O(1)
    atomicAdd(acc1 + (long)d * D1 + lane, ex * xw1[(long)s * D1 + lane]);
    if ((lane & 7) == 0) atomicAdd(s1 + d * 8 + h, ex);
}

// ---------------- K5: node mid layer: ELU, xw2 = h@W2, al2 projections ----------------
__global__ __launch_bounds__(256) void k_mid(const float* __restrict__ acc1,
                                             const float* __restrict__ s1,
                                             const float* __restrict__ b1,
                                             const float* __restrict__ W2,
                                             const float* __restrict__ a2s,
                                             const float* __restrict__ a2d,
                                             float* __restrict__ xw2,
                                             float* __restrict__ al2s,
                                             float* __restrict__ al2d) {
    __shared__ float w2s[D1 * D2];
    __shared__ float b1s[D1];
    for (int i = threadIdx.x; i < D1 * D2; i += 256) w2s[i] = W2[i];
    if (threadIdx.x < D1) b1s[threadIdx.x] = b1[threadIdx.x];
    __syncthreads();
    const int n = blockIdx.x * 256 + threadIdx.x;
    if (n >= N_NODESC) return;

    float hbuf[D1];
#pragma unroll
    for (int hh = 0; hh < 8; hh++) {
        const float inv = 1.0f / (s1[n * 8 + hh] + 1e-16f);
#pragma unroll
        for (int c = 0; c < 8; c++) {
            const float v = acc1[(long)n * D1 + hh * 8 + c] * inv + b1s[hh * 8 + c];
            hbuf[hh * 8 + c] = v > 0.f ? v : expm1f(v);   // ELU(alpha=1)
        }
    }
    float o[D2];
#pragma unroll
    for (int j = 0; j < D2; j++) o[j] = 0.f;
#pragma unroll
    for (int c = 0; c < D1; c++) {
        const float hv = hbuf[c];
        const float* wr = w2s + c * D2;
#pragma unroll
        for (int j = 0; j < D2; j++) o[j] += hv * wr[j];
    }
#pragma unroll
    for (int j = 0; j < D2; j++) xw2[(long)n * D2 + j] = o[j];
#pragma unroll
    for (int hh = 0; hh < 8; hh++) {
        al2s[n * 8 + hh] = o[hh * 3] * a2s[hh * 3] + o[hh * 3 + 1] * a2s[hh * 3 + 1] + o[hh * 3 + 2] * a2s[hh * 3 + 2];
        al2d[n * 8 + hh] = o[hh * 3] * a2d[hh * 3] + o[hh * 3 + 1] * a2d[hh * 3 + 1] + o[hh * 3 + 2] * a2d[hh * 3 + 2];
    }
}

// ---------------- K7: edge aggregation, layer 2 (24 lanes per edge) ----------------
__global__ __launch_bounds__(256) void k_edge2(const int* __restrict__ ei,
                                               const float* __restrict__ al2s,
                                               const float* __restrict__ al2d,
                                               const float* __restrict__ xw2,
                                               float* __restrict__ acc2,
                                               float* __restrict__ s2) {
    const long gidl = (long)blockIdx.x * 256 + threadIdx.x;
    if (gidl >= (long)E_TOT * 24) return;
    const unsigned g = (unsigned)gidl;
    const int e = (int)(g / 24u);
    const int j = (int)(g - (unsigned)e * 24u);
    const int h = j / 3;
    int s, d;
    if (e < N_EDGESC) { s = ei[e]; d = ei[N_EDGESC + e]; }
    else { s = d = e - N_EDGESC; }
    float ev = al2s[s * 8 + h] + al2d[d * 8 + h];
    ev = ev > 0.f ? ev : 0.2f * ev;
    const float ex = expf(ev);
    atomicAdd(acc2 + (long)d * D2 + j, ex * xw2[(long)s * D2 + j]);
    if (j - h * 3 == 0) atomicAdd(s2 + d * 8 + h, ex);
}

// ---------------- K8: mean over heads + bias + softmax ----------------
__global__ __launch_bounds__(256) void k_out(const float* __restrict__ acc2,
                                             const float* __restrict__ s2,
                                             const float* __restrict__ b2,
                                             float* __restrict__ out) {
    const int n = blockIdx.x * 256 + threadIdx.x;
    if (n >= N_NODESC) return;
    float lg[3] = {0.f, 0.f, 0.f};
#pragma unroll
    for (int hh = 0; hh < 8; hh++) {
        const float inv = 1.0f / (s2[n * 8 + hh] + 1e-16f);
#pragma unroll
        for (int c = 0; c < 3; c++) lg[c] += acc2[(long)n * D2 + hh * 3 + c] * inv;
    }
#pragma unroll
    for (int c = 0; c < 3; c++) lg[c] = lg[c] * 0.125f + b2[c];
    const float m = fmaxf(lg[0], fmaxf(lg[1], lg[2]));
    const float e0 = expf(lg[0] - m), e1 = expf(lg[1] - m), e2 = expf(lg[2] - m);
    const float inv = 1.0f / (e0 + e1 + e2);
    out[(long)n * 3 + 0] = e0 * inv;
    out[(long)n * 3 + 1] = e1 * inv;
    out[(long)n * 3 + 2] = e2 * inv;
}

extern "C" void kernel_launch(void* const* d_in, const int* in_sizes, int n_in,
                              void* d_out, int out_size, void* d_ws, size_t ws_size,
                              hipStream_t stream) {
    const float* x   = (const float*)d_in[0];
    const float* W1  = (const float*)d_in[1];
    const float* a1s = (const float*)d_in[2];
    const float* a1d = (const float*)d_in[3];
    const float* b1  = (const float*)d_in[4];
    const float* W2  = (const float*)d_in[5];
    const float* a2s = (const float*)d_in[6];
    const float* a2d = (const float*)d_in[7];
    const float* b2  = (const float*)d_in[8];
    const int*   ei  = (const int*)d_in[9];
    float* out = (float*)d_out;

    float* ws   = (float*)d_ws;
    float* xw1  = ws;                  // 6.4M floats
    float* al1s = xw1 + 6400000;       // 0.8M
    float* al1d = al1s + 800000;       // 0.8M
    float* s1   = al1d + 800000;       // 0.8M
    float* acc1 = s1 + 800000;         // 6.4M
    float* xw2  = acc1 + 6400000;      // 2.4M
    float* al2s = xw2 + 2400000;       // 0.8M
    float* al2d = al2s + 800000;       // 0.8M
    float* s2   = al2d + 800000;       // 0.8M
    float* acc2 = s2 + 800000;         // 2.4M
    // total 22.4M floats = 89.6 MB of d_ws

    // zero the atomic accumulators (s1+acc1 contiguous, s2+acc2 contiguous)
    hipMemsetAsync(s1, 0, (size_t)(800000 + 6400000) * sizeof(float), stream);
    hipMemsetAsync(s2, 0, (size_t)(800000 + 2400000) * sizeof(float), stream);

    k_gemm1<<<(N_NODESC + 63) / 64, 256, 0, stream>>>(x, W1, xw1);
    k_al1<<<(N_NODESC * H1C + 255) / 256, 256, 0, stream>>>(xw1, a1s, a1d, al1s, al1d);
    k_edge1<<<(int)(((long)E_TOT * 64 + 255) / 256), 256, 0, stream>>>(ei, al1s, al1d, xw1, acc1, s1);
    k_mid<<<(N_NODESC + 255) / 256, 256, 0, stream>>>(acc1, s1, b1, W2, a2s, a2d, xw2, al2s, al2d);
    k_edge2<<<(int)(((long)E_TOT * 24 + 255) / 256), 256, 0, stream>>>(ei, al2s, al2d, xw2, acc2, s2);
    k_out<<<(N_NODESC + 255) / 256, 256, 0, stream>>>(acc2, s2, b2, out);
}

// Round 2
// 987.308 us; speedup vs baseline: 1.1739x; 1.1739x over previous
//
#include <hip/hip_runtime.h>
#include <math.h>

#define N_NODESC 100000
#define N_EDGESC 1600000
#define E_TOT    1700000   // incl. self loops
#define IN_CH    500
#define D1 64
#define H1C 8
#define D2 24
#define H2C 8

// ================= edge sort (counting sort by dst) =================
__global__ __launch_bounds__(256) void k_hist(const int* __restrict__ ei,
                                              int* __restrict__ deg) {
    const int e = blockIdx.x * 256 + threadIdx.x;
    if (e >= E_TOT) return;
    const int d = (e < N_EDGESC) ? ei[N_EDGESC + e] : (e - N_EDGESC);
    atomicAdd(deg + d, 1);
}

// single-block exclusive scan over 100000 degrees -> off[0..N], cursor copy
__global__ __launch_bounds__(1024) void k_scan(const int* __restrict__ deg,
                                               int* __restrict__ off,
                                               int* __restrict__ cursor) {
    __shared__ int part[1024];
    const int t = threadIdx.x;
    const int lo = t * 98;
    const int hi = min(lo + 98, N_NODESC);
    int s = 0;
    for (int i = lo; i < hi; i++) s += deg[i];
    part[t] = s;
    __syncthreads();
    for (int d = 1; d < 1024; d <<= 1) {
        int v = (t >= d) ? part[t - d] : 0;
        __syncthreads();
        part[t] += v;
        __syncthreads();
    }
    int run = (t > 0) ? part[t - 1] : 0;
    for (int i = lo; i < hi; i++) {
        off[i] = run;
        cursor[i] = run;
        run += deg[i];
    }
    if (t == 1023) off[N_NODESC] = part[1023];
}

__global__ __launch_bounds__(256) void k_scatter(const int* __restrict__ ei,
                                                 int* __restrict__ cursor,
                                                 int* __restrict__ srt_src) {
    const int e = blockIdx.x * 256 + threadIdx.x;
    if (e >= E_TOT) return;
    int s, d;
    if (e < N_EDGESC) { s = ei[e]; d = ei[N_EDGESC + e]; }
    else { s = d = e - N_EDGESC; }
    const int pos = atomicAdd(cursor + d, 1);
    srt_src[pos] = s;
}

// ================= K1: xw1 = x @ W1 (fp32, 64x64 tile, 4x4/thread) =================
__global__ __launch_bounds__(256) void k_gemm1(const float* __restrict__ x,
                                               const float* __restrict__ W1,
                                               float* __restrict__ xw1) {
    __shared__ float xs[64 * 64];   // [kk][row]
    __shared__ float wcs[64 * 64];  // [kk][col]
    const int t = threadIdx.x;
    const int rowBase = blockIdx.x * 64;
    const int tr = t >> 4;
    const int tc = t & 15;
    const int lr = t >> 2;
    const int lq = t & 3;

    float acc[4][4];
#pragma unroll
    for (int i = 0; i < 4; i++)
#pragma unroll
        for (int j = 0; j < 4; j++) acc[i][j] = 0.f;

    for (int k0 = 0; k0 < IN_CH; k0 += 64) {
        __syncthreads();
        {
            const int row = rowBase + lr;
#pragma unroll
            for (int i = 0; i < 4; i++) {
                const int kk = lq * 16 + i * 4;
                const int k = k0 + kk;
                float4 v = make_float4(0.f, 0.f, 0.f, 0.f);
                if (row < N_NODESC && k < IN_CH)
                    v = *(const float4*)(x + (long)row * IN_CH + k);
                xs[(kk + 0) * 64 + lr] = v.x;
                xs[(kk + 1) * 64 + lr] = v.y;
                xs[(kk + 2) * 64 + lr] = v.z;
                xs[(kk + 3) * 64 + lr] = v.w;
            }
        }
        {
#pragma unroll
            for (int i = 0; i < 4; i++) {
                const int o = t * 16 + i * 4;
                float4 v = make_float4(0.f, 0.f, 0.f, 0.f);
                if (k0 + (o >> 6) < IN_CH)
                    v = *(const float4*)(W1 + k0 * 64 + o);
                *(float4*)(wcs + o) = v;
            }
        }
        __syncthreads();
#pragma unroll
        for (int kk = 0; kk < 64; kk++) {
            const float4 xv = *(const float4*)(xs + kk * 64 + tr * 4);
            const float4 wv = *(const float4*)(wcs + kk * 64 + tc * 4);
            acc[0][0] += xv.x * wv.x; acc[0][1] += xv.x * wv.y; acc[0][2] += xv.x * wv.z; acc[0][3] += xv.x * wv.w;
            acc[1][0] += xv.y * wv.x; acc[1][1] += xv.y * wv.y; acc[1][2] += xv.y * wv.z; acc[1][3] += xv.y * wv.w;
            acc[2][0] += xv.z * wv.x; acc[2][1] += xv.z * wv.y; acc[2][2] += xv.z * wv.z; acc[2][3] += xv.z * wv.w;
            acc[3][0] += xv.w * wv.x; acc[3][1] += xv.w * wv.y; acc[3][2] += xv.w * wv.z; acc[3][3] += xv.w * wv.w;
        }
    }
#pragma unroll
    for (int rr = 0; rr < 4; rr++) {
        const int row = rowBase + tr * 4 + rr;
        if (row < N_NODESC)
            *(float4*)(xw1 + (long)row * D1 + tc * 4) =
                make_float4(acc[rr][0], acc[rr][1], acc[rr][2], acc[rr][3]);
    }
}

// ================= K2: attention logit projections, layer 1 =================
__global__ __launch_bounds__(256) void k_al1(const float* __restrict__ xw1,
                                             const float* __restrict__ a1s,
                                             const float* __restrict__ a1d,
                                             float* __restrict__ al1s,
                                             float* __restrict__ al1d) {
    const int gid = blockIdx.x * 256 + threadIdx.x;
    if (gid >= N_NODESC * H1C) return;
    const int n = gid >> 3, h = gid & 7;
    const float4* p = (const float4*)(xw1 + (long)n * D1 + h * 8);
    const float4 v0 = p[0], v1 = p[1];
    const float4* as = (const float4*)(a1s + h * 8);
    const float4 s0 = as[0], s1 = as[1];
    const float4* ad = (const float4*)(a1d + h * 8);
    const float4 d0 = ad[0], d1 = ad[1];
    al1s[gid] = v0.x * s0.x + v0.y * s0.y + v0.z * s0.z + v0.w * s0.w +
                v1.x * s1.x + v1.y * s1.y + v1.z * s1.z + v1.w * s1.w;
    al1d[gid] = v0.x * d0.x + v0.y * d0.y + v0.z * d0.z + v0.w * d0.w +
                v1.x * d1.x + v1.y * d1.y + v1.z * d1.z + v1.w * d1.w;
}

// ================= K3: gather-aggregate layer 1 (wave/node, 4 edges/iter) =================
// lane = esub*16 + q ; lane q covers channels 4q..4q+3 (head q>>1); esub strides edges.
// Epilogue fuses: alpha-normalize + bias + ELU -> hmid.
__global__ __launch_bounds__(256) void k_gat1(const int* __restrict__ off,
                                              const int* __restrict__ srt_src,
                                              const float* __restrict__ al1s,
                                              const float* __restrict__ al1d,
                                              const float* __restrict__ xw1,
                                              const float* __restrict__ b1,
                                              float* __restrict__ hmid) {
    const int tid = threadIdx.x;
    const int lane = tid & 63;
    const int wid = tid >> 6;
    const int n = blockIdx.x * 4 + wid;   // N_NODESC % 4 == 0
    const int esub = lane >> 4;
    const int q = lane & 15;
    const int h = q >> 1;

    const float ald = al1d[n * 8 + h];
    const int kend = off[n + 1];

    float4 acc = make_float4(0.f, 0.f, 0.f, 0.f);
    float ssum = 0.f;
    for (int k = off[n] + esub; k < kend; k += 4) {
        const int s = srt_src[k];
        float ev = al1s[s * 8 + h] + ald;
        ev = ev > 0.f ? ev : 0.2f * ev;
        const float ex = expf(ev);
        const float4 v = *(const float4*)(xw1 + (long)s * D1 + q * 4);
        acc.x += ex * v.x; acc.y += ex * v.y; acc.z += ex * v.z; acc.w += ex * v.w;
        ssum += ex;
    }
    // reduce across the 4 esub groups (lanes differing in bits 4,5)
#pragma unroll
    for (int m = 16; m < 64; m <<= 1) {
        acc.x += __shfl_xor(acc.x, m, 64);
        acc.y += __shfl_xor(acc.y, m, 64);
        acc.z += __shfl_xor(acc.z, m, 64);
        acc.w += __shfl_xor(acc.w, m, 64);
        ssum  += __shfl_xor(ssum,  m, 64);
    }
    if (esub == 0) {
        const float inv = 1.0f / (ssum + 1e-16f);
        const float4 bb = *(const float4*)(b1 + q * 4);
        float4 r;
        r.x = acc.x * inv + bb.x; r.x = r.x > 0.f ? r.x : expm1f(r.x);
        r.y = acc.y * inv + bb.y; r.y = r.y > 0.f ? r.y : expm1f(r.y);
        r.z = acc.z * inv + bb.z; r.z = r.z > 0.f ? r.z : expm1f(r.z);
        r.w = acc.w * inv + bb.w; r.w = r.w > 0.f ? r.w : expm1f(r.w);
        *(float4*)(hmid + (long)n * D1 + q * 4) = r;
    }
}

// ================= K4: xw2 = hmid @ W2, al2 projections =================
__global__ __launch_bounds__(256) void k_mid2(const float* __restrict__ hmid,
                                              const float* __restrict__ W2,
                                              const float* __restrict__ a2s,
                                              const float* __restrict__ a2d,
                                              float* __restrict__ xw2,
                                              float* __restrict__ al2s,
                                              float* __restrict__ al2d) {
    __shared__ float w2s[D1 * D2];
    for (int i = threadIdx.x; i < D1 * D2; i += 256) w2s[i] = W2[i];
    __syncthreads();
    const int n = blockIdx.x * 256 + threadIdx.x;
    if (n >= N_NODESC) return;

    float o[D2];
#pragma unroll
    for (int j = 0; j < D2; j++) o[j] = 0.f;
#pragma unroll
    for (int c4 = 0; c4 < D1; c4 += 4) {
        const float4 hv = *(const float4*)(hmid + (long)n * D1 + c4);
        const float* wr = w2s + c4 * D2;
#pragma unroll
        for (int j = 0; j < D2; j++) {
            o[j] += hv.x * wr[j] + hv.y * wr[D2 + j] + hv.z * wr[2 * D2 + j] + hv.w * wr[3 * D2 + j];
        }
    }
#pragma unroll
    for (int j = 0; j < D2; j++) xw2[(long)n * D2 + j] = o[j];
#pragma unroll
    for (int hh = 0; hh < 8; hh++) {
        al2s[n * 8 + hh] = o[hh * 3] * a2s[hh * 3] + o[hh * 3 + 1] * a2s[hh * 3 + 1] + o[hh * 3 + 2] * a2s[hh * 3 + 2];
        al2d[n * 8 + hh] = o[hh * 3] * a2d[hh * 3] + o[hh * 3 + 1] * a2d[hh * 3 + 1] + o[hh * 3 + 2] * a2d[hh * 3 + 2];
    }
}

// ================= K5: gather-aggregate layer 2 + head-mean + softmax =================
// lanes 0..47: esub = lane/24 in {0,1}, j = lane%24, head = j/3. lanes 48..63 idle.
__global__ __launch_bounds__(256) void k_gat2(const int* __restrict__ off,
                                              const int* __restrict__ srt_src,
                                              const float* __restrict__ al2s,
                                              const float* __restrict__ al2d,
                                              const float* __restrict__ xw2,
                                              const float* __restrict__ b2,
                                              float* __restrict__ out) {
    __shared__ float sm[4][24];
    const int tid = threadIdx.x;
    const int lane = tid & 63;
    const int wid = tid >> 6;
    const int n = blockIdx.x * 4 + wid;
    const int esub = lane / 24;          // 0,1,2
    const int j = lane - esub * 24;
    const int h = j / 3;

    float acc = 0.f, ssum = 0.f;
    if (esub < 2) {
        const float ald = al2d[n * 8 + h];
        const int kend = off[n + 1];
        for (int k = off[n] + esub; k < kend; k += 2) {
            const int s = srt_src[k];
            float ev = al2s[s * 8 + h] + ald;
            ev = ev > 0.f ? ev : 0.2f * ev;
            const float ex = expf(ev);
            acc += ex * xw2[(long)s * D2 + j];
            ssum += ex;
        }
    }
    // fold esub1 into esub0
    acc  += __shfl_down(acc, 24, 64);
    ssum += __shfl_down(ssum, 24, 64);
    if (lane < 24) sm[wid][j] = acc / (ssum + 1e-16f);
    __syncthreads();
    float lg = 0.f;
    if (lane < 3) {
#pragma unroll
        for (int hh = 0; hh < 8; hh++) lg += sm[wid][hh * 3 + lane];
        lg = lg * 0.125f + b2[lane];
    }
    const float l0 = __shfl(lg, 0, 64);
    const float l1 = __shfl(lg, 1, 64);
    const float l2 = __shfl(lg, 2, 64);
    if (lane < 3) {
        const float m = fmaxf(l0, fmaxf(l1, l2));
        const float denom = expf(l0 - m) + expf(l1 - m) + expf(l2 - m);
        out[(long)n * 3 + lane] = expf(lg - m) / denom;
    }
}

extern "C" void kernel_launch(void* const* d_in, const int* in_sizes, int n_in,
                              void* d_out, int out_size, void* d_ws, size_t ws_size,
                              hipStream_t stream) {
    const float* x   = (const float*)d_in[0];
    const float* W1  = (const float*)d_in[1];
    const float* a1s = (const float*)d_in[2];
    const float* a1d = (const float*)d_in[3];
    const float* b1  = (const float*)d_in[4];
    const float* W2  = (const float*)d_in[5];
    const float* a2s = (const float*)d_in[6];
    const float* a2d = (const float*)d_in[7];
    const float* b2  = (const float*)d_in[8];
    const int*   ei  = (const int*)d_in[9];
    float* out = (float*)d_out;

    float* ws   = (float*)d_ws;
    float* xw1  = ws;                  // 6,400,000
    float* al1s = xw1  + 6400000;      //   800,000
    float* al1d = al1s + 800000;       //   800,000
    float* hmid = al1d + 800000;       // 6,400,000
    float* xw2  = hmid + 6400000;      // 2,400,000
    float* al2s = xw2  + 2400000;      //   800,000
    float* al2d = al2s + 800000;       //   800,000
    int* deg    = (int*)(al2d + 800000);   //   100,000
    int* off    = deg + 100000;            //   100,001
    int* cursor = off + 100001;            //   100,000
    int* srt    = cursor + 100000;         // 1,700,000
    // total ~82 MB

    hipMemsetAsync(deg, 0, (size_t)N_NODESC * sizeof(int), stream);

    const int EB = (E_TOT + 255) / 256;
    k_hist<<<EB, 256, 0, stream>>>(ei, deg);
    k_scan<<<1, 1024, 0, stream>>>(deg, off, cursor);
    k_scatter<<<EB, 256, 0, stream>>>(ei, cursor, srt);

    k_gemm1<<<(N_NODESC + 63) / 64, 256, 0, stream>>>(x, W1, xw1);
    k_al1<<<(N_NODESC * H1C + 255) / 256, 256, 0, stream>>>(xw1, a1s, a1d, al1s, al1d);
    k_gat1<<<N_NODESC / 4, 256, 0, stream>>>(off, srt, al1s, al1d, xw1, b1, hmid);
    k_mid2<<<(N_NODESC + 255) / 256, 256, 0, stream>>>(hmid, W2, a2s, a2d, xw2, al2s, al2d);
    k_gat2<<<N_NODESC / 4, 256, 0, stream>>>(off, srt, al2s, al2d, xw2, b2, out);
}

// Round 3
// 768.074 us; speedup vs baseline: 1.5090x; 1.2854x over previous
//
#include <hip/hip_runtime.h>
#include <math.h>

#define N_NODESC 100000
#define N_EDGESC 1600000
#define E_TOT    1700000   // incl. self loops
#define IN_CH    500
#define D1 64
#define H1C 8
#define D2 24
#define H2C 8
#define NBLK 391           // ceil(N_NODESC/256)

// ================= edge sort (counting sort by dst) =================
__global__ __launch_bounds__(256) void k_hist(const int* __restrict__ ei,
                                              int* __restrict__ deg) {
    const int e = blockIdx.x * 256 + threadIdx.x;
    if (e >= E_TOT) return;
    const int d = (e < N_EDGESC) ? ei[N_EDGESC + e] : (e - N_EDGESC);
    atomicAdd(deg + d, 1);
}

// phase 1: per-block sums of 256 degrees
__global__ __launch_bounds__(256) void k_bsum(const int* __restrict__ deg,
                                              int* __restrict__ bsum) {
    const int i = blockIdx.x * 256 + threadIdx.x;
    int v = (i < N_NODESC) ? deg[i] : 0;
#pragma unroll
    for (int m = 1; m < 64; m <<= 1) v += __shfl_xor(v, m, 64);
    __shared__ int ws[4];
    if ((threadIdx.x & 63) == 0) ws[threadIdx.x >> 6] = v;
    __syncthreads();
    if (threadIdx.x == 0) bsum[blockIdx.x] = ws[0] + ws[1] + ws[2] + ws[3];
}

// phase 2: single-block scan over NBLK block sums (tiny)
__global__ __launch_bounds__(512) void k_bscan(const int* __restrict__ bsum,
                                               int* __restrict__ boff) {
    __shared__ int sm[512];
    const int t = threadIdx.x;
    const int v = (t < NBLK) ? bsum[t] : 0;
    sm[t] = v;
    __syncthreads();
    for (int d = 1; d < 512; d <<= 1) {
        int u = (t >= d) ? sm[t - d] : 0;
        __syncthreads();
        sm[t] += u;
        __syncthreads();
    }
    if (t < NBLK) boff[t] = sm[t] - v;   // exclusive
}

// phase 3: in-block scan + block offset -> off, cursor
__global__ __launch_bounds__(256) void k_off(const int* __restrict__ deg,
                                             const int* __restrict__ boff,
                                             int* __restrict__ off,
                                             int* __restrict__ cursor) {
    __shared__ int sm[256];
    const int t = threadIdx.x;
    const int i = blockIdx.x * 256 + t;
    const int v = (i < N_NODESC) ? deg[i] : 0;
    sm[t] = v;
    __syncthreads();
    for (int d = 1; d < 256; d <<= 1) {
        int u = (t >= d) ? sm[t - d] : 0;
        __syncthreads();
        sm[t] += u;
        __syncthreads();
    }
    if (i < N_NODESC) {
        const int ex = boff[blockIdx.x] + sm[t] - v;
        off[i] = ex;
        cursor[i] = ex;
    }
    if (i == 0) off[N_NODESC] = E_TOT;
}

__global__ __launch_bounds__(256) void k_scatter(const int* __restrict__ ei,
                                                 int* __restrict__ cursor,
                                                 int* __restrict__ srt_src) {
    const int e = blockIdx.x * 256 + threadIdx.x;
    if (e >= E_TOT) return;
    int s, d;
    if (e < N_EDGESC) { s = ei[e]; d = ei[N_EDGESC + e]; }
    else { s = d = e - N_EDGESC; }
    const int pos = atomicAdd(cursor + d, 1);
    srt_src[pos] = s;
}

// ================= K1: xw1 = x @ W1 (fp32, 64x64 tile, 4x4/thread) =================
__global__ __launch_bounds__(256) void k_gemm1(const float* __restrict__ x,
                                               const float* __restrict__ W1,
                                               float* __restrict__ xw1) {
    __shared__ float xs[64 * 64];   // [kk][row]
    __shared__ float wcs[64 * 64];  // [kk][col]
    const int t = threadIdx.x;
    const int rowBase = blockIdx.x * 64;
    const int tr = t >> 4;
    const int tc = t & 15;
    const int lr = t >> 2;
    const int lq = t & 3;

    float acc[4][4];
#pragma unroll
    for (int i = 0; i < 4; i++)
#pragma unroll
        for (int j = 0; j < 4; j++) acc[i][j] = 0.f;

    for (int k0 = 0; k0 < IN_CH; k0 += 64) {
        __syncthreads();
        {
            const int row = rowBase + lr;
#pragma unroll
            for (int i = 0; i < 4; i++) {
                const int kk = lq * 16 + i * 4;
                const int k = k0 + kk;
                float4 v = make_float4(0.f, 0.f, 0.f, 0.f);
                if (row < N_NODESC && k < IN_CH)
                    v = *(const float4*)(x + (long)row * IN_CH + k);
                xs[(kk + 0) * 64 + lr] = v.x;
                xs[(kk + 1) * 64 + lr] = v.y;
                xs[(kk + 2) * 64 + lr] = v.z;
                xs[(kk + 3) * 64 + lr] = v.w;
            }
        }
        {
#pragma unroll
            for (int i = 0; i < 4; i++) {
                const int o = t * 16 + i * 4;
                float4 v = make_float4(0.f, 0.f, 0.f, 0.f);
                if (k0 + (o >> 6) < IN_CH)
                    v = *(const float4*)(W1 + k0 * 64 + o);
                *(float4*)(wcs + o) = v;
            }
        }
        __syncthreads();
#pragma unroll
        for (int kk = 0; kk < 64; kk++) {
            const float4 xv = *(const float4*)(xs + kk * 64 + tr * 4);
            const float4 wv = *(const float4*)(wcs + kk * 64 + tc * 4);
            acc[0][0] += xv.x * wv.x; acc[0][1] += xv.x * wv.y; acc[0][2] += xv.x * wv.z; acc[0][3] += xv.x * wv.w;
            acc[1][0] += xv.y * wv.x; acc[1][1] += xv.y * wv.y; acc[1][2] += xv.y * wv.z; acc[1][3] += xv.y * wv.w;
            acc[2][0] += xv.z * wv.x; acc[2][1] += xv.z * wv.y; acc[2][2] += xv.z * wv.z; acc[2][3] += xv.z * wv.w;
            acc[3][0] += xv.w * wv.x; acc[3][1] += xv.w * wv.y; acc[3][2] += xv.w * wv.z; acc[3][3] += xv.w * wv.w;
        }
    }
#pragma unroll
    for (int rr = 0; rr < 4; rr++) {
        const int row = rowBase + tr * 4 + rr;
        if (row < N_NODESC)
            *(float4*)(xw1 + (long)row * D1 + tc * 4) =
                make_float4(acc[rr][0], acc[rr][1], acc[rr][2], acc[rr][3]);
    }
}

// ================= K2: attention logit projections, layer 1 =================
__global__ __launch_bounds__(256) void k_al1(const float* __restrict__ xw1,
                                             const float* __restrict__ a1s,
                                             const float* __restrict__ a1d,
                                             float* __restrict__ al1s,
                                             float* __restrict__ al1d) {
    const int gid = blockIdx.x * 256 + threadIdx.x;
    if (gid >= N_NODESC * H1C) return;
    const int n = gid >> 3, h = gid & 7;
    const float4* p = (const float4*)(xw1 + (long)n * D1 + h * 8);
    const float4 v0 = p[0], v1 = p[1];
    const float4* as = (const float4*)(a1s + h * 8);
    const float4 s0 = as[0], s1 = as[1];
    const float4* ad = (const float4*)(a1d + h * 8);
    const float4 d0 = ad[0], d1 = ad[1];
    al1s[gid] = v0.x * s0.x + v0.y * s0.y + v0.z * s0.z + v0.w * s0.w +
                v1.x * s1.x + v1.y * s1.y + v1.z * s1.z + v1.w * s1.w;
    al1d[gid] = v0.x * d0.x + v0.y * d0.y + v0.z * d0.z + v0.w * d0.w +
                v1.x * d1.x + v1.y * d1.y + v1.z * d1.z + v1.w * d1.w;
}

// ================= K3: gather-aggregate layer 1 (wave/node, 4 edges/iter) =================
__global__ __launch_bounds__(256) void k_gat1(const int* __restrict__ off,
                                              const int* __restrict__ srt_src,
                                              const float* __restrict__ al1s,
                                              const float* __restrict__ al1d,
                                              const float* __restrict__ xw1,
                                              const float* __restrict__ b1,
                                              float* __restrict__ hmid) {
    const int tid = threadIdx.x;
    const int lane = tid & 63;
    const int wid = tid >> 6;
    const int n = blockIdx.x * 4 + wid;   // N_NODESC % 4 == 0
    const int esub = lane >> 4;
    const int q = lane & 15;
    const int h = q >> 1;

    const float ald = al1d[n * 8 + h];
    const int kend = off[n + 1];

    float4 acc = make_float4(0.f, 0.f, 0.f, 0.f);
    float ssum = 0.f;
    for (int k = off[n] + esub; k < kend; k += 4) {
        const int s = srt_src[k];
        float ev = al1s[s * 8 + h] + ald;
        ev = ev > 0.f ? ev : 0.2f * ev;
        const float ex = expf(ev);
        const float4 v = *(const float4*)(xw1 + (long)s * D1 + q * 4);
        acc.x += ex * v.x; acc.y += ex * v.y; acc.z += ex * v.z; acc.w += ex * v.w;
        ssum += ex;
    }
#pragma unroll
    for (int m = 16; m < 64; m <<= 1) {
        acc.x += __shfl_xor(acc.x, m, 64);
        acc.y += __shfl_xor(acc.y, m, 64);
        acc.z += __shfl_xor(acc.z, m, 64);
        acc.w += __shfl_xor(acc.w, m, 64);
        ssum  += __shfl_xor(ssum,  m, 64);
    }
    if (esub == 0) {
        const float inv = 1.0f / (ssum + 1e-16f);
        const float4 bb = *(const float4*)(b1 + q * 4);
        float4 r;
        r.x = acc.x * inv + bb.x; r.x = r.x > 0.f ? r.x : expm1f(r.x);
        r.y = acc.y * inv + bb.y; r.y = r.y > 0.f ? r.y : expm1f(r.y);
        r.z = acc.z * inv + bb.z; r.z = r.z > 0.f ? r.z : expm1f(r.z);
        r.w = acc.w * inv + bb.w; r.w = r.w > 0.f ? r.w : expm1f(r.w);
        *(float4*)(hmid + (long)n * D1 + q * 4) = r;
    }
}

// ================= K4: xw2 = hmid @ W2, al2 projections =================
__global__ __launch_bounds__(256) void k_mid2(const float* __restrict__ hmid,
                                              const float* __restrict__ W2,
                                              const float* __restrict__ a2s,
                                              const float* __restrict__ a2d,
                                              float* __restrict__ xw2,
                                              float* __restrict__ al2s,
                                              float* __restrict__ al2d) {
    __shared__ float w2s[D1 * D2];
    for (int i = threadIdx.x; i < D1 * D2; i += 256) w2s[i] = W2[i];
    __syncthreads();
    const int n = blockIdx.x * 256 + threadIdx.x;
    if (n >= N_NODESC) return;

    float o[D2];
#pragma unroll
    for (int j = 0; j < D2; j++) o[j] = 0.f;
#pragma unroll
    for (int c4 = 0; c4 < D1; c4 += 4) {
        const float4 hv = *(const float4*)(hmid + (long)n * D1 + c4);
        const float* wr = w2s + c4 * D2;
#pragma unroll
        for (int j = 0; j < D2; j++) {
            o[j] += hv.x * wr[j] + hv.y * wr[D2 + j] + hv.z * wr[2 * D2 + j] + hv.w * wr[3 * D2 + j];
        }
    }
#pragma unroll
    for (int j = 0; j < D2; j++) xw2[(long)n * D2 + j] = o[j];
#pragma unroll
    for (int hh = 0; hh < 8; hh++) {
        al2s[n * 8 + hh] = o[hh * 3] * a2s[hh * 3] + o[hh * 3 + 1] * a2s[hh * 3 + 1] + o[hh * 3 + 2] * a2s[hh * 3 + 2];
        al2d[n * 8 + hh] = o[hh * 3] * a2d[hh * 3] + o[hh * 3 + 1] * a2d[hh * 3 + 1] + o[hh * 3 + 2] * a2d[hh * 3 + 2];
    }
}

// ================= K5: gather-aggregate layer 2 + head-mean + softmax =================
__global__ __launch_bounds__(256) void k_gat2(const int* __restrict__ off,
                                              const int* __restrict__ srt_src,
                                              const float* __restrict__ al2s,
                                              const float* __restrict__ al2d,
                                              const float* __restrict__ xw2,
                                              const float* __restrict__ b2,
                                              float* __restrict__ out) {
    __shared__ float sm[4][24];
    const int tid = threadIdx.x;
    const int lane = tid & 63;
    const int wid = tid >> 6;
    const int n = blockIdx.x * 4 + wid;
    const int esub = lane / 24;          // 0,1,2
    const int j = lane - esub * 24;
    const int h = j / 3;

    float acc = 0.f, ssum = 0.f;
    if (esub < 2) {
        const float ald = al2d[n * 8 + h];
        const int kend = off[n + 1];
        for (int k = off[n] + esub; k < kend; k += 2) {
            const int s = srt_src[k];
            float ev = al2s[s * 8 + h] + ald;
            ev = ev > 0.f ? ev : 0.2f * ev;
            const float ex = expf(ev);
            acc += ex * xw2[(long)s * D2 + j];
            ssum += ex;
        }
    }
    acc  += __shfl_down(acc, 24, 64);
    ssum += __shfl_down(ssum, 24, 64);
    if (lane < 24) sm[wid][j] = acc / (ssum + 1e-16f);
    __syncthreads();
    float lg = 0.f;
    if (lane < 3) {
#pragma unroll
        for (int hh = 0; hh < 8; hh++) lg += sm[wid][hh * 3 + lane];
        lg = lg * 0.125f + b2[lane];
    }
    const float l0 = __shfl(lg, 0, 64);
    const float l1 = __shfl(lg, 1, 64);
    const float l2 = __shfl(lg, 2, 64);
    if (lane < 3) {
        const float m = fmaxf(l0, fmaxf(l1, l2));
        const float denom = expf(l0 - m) + expf(l1 - m) + expf(l2 - m);
        out[(long)n * 3 + lane] = expf(lg - m) / denom;
    }
}

extern "C" void kernel_launch(void* const* d_in, const int* in_sizes, int n_in,
                              void* d_out, int out_size, void* d_ws, size_t ws_size,
                              hipStream_t stream) {
    const float* x   = (const float*)d_in[0];
    const float* W1  = (const float*)d_in[1];
    const float* a1s = (const float*)d_in[2];
    const float* a1d = (const float*)d_in[3];
    const float* b1  = (const float*)d_in[4];
    const float* W2  = (const float*)d_in[5];
    const float* a2s = (const float*)d_in[6];
    const float* a2d = (const float*)d_in[7];
    const float* b2  = (const float*)d_in[8];
    const int*   ei  = (const int*)d_in[9];
    float* out = (float*)d_out;

    float* ws   = (float*)d_ws;
    float* xw1  = ws;                  // 6,400,000
    float* al1s = xw1  + 6400000;      //   800,000
    float* al1d = al1s + 800000;       //   800,000
    float* hmid = al1d + 800000;       // 6,400,000
    float* xw2  = hmid + 6400000;      // 2,400,000
    float* al2s = xw2  + 2400000;      //   800,000
    float* al2d = al2s + 800000;       //   800,000
    int* deg    = (int*)(al2d + 800000);   //   100,000
    int* off    = deg + 100000;            //   100,001
    int* cursor = off + 100001;            //   100,000
    int* srt    = cursor + 100000;         // 1,700,000
    int* bsum   = srt + 1700000;           //   NBLK
    int* boff   = bsum + NBLK;             //   NBLK

    hipMemsetAsync(deg, 0, (size_t)N_NODESC * sizeof(int), stream);

    const int EB = (E_TOT + 255) / 256;
    k_hist<<<EB, 256, 0, stream>>>(ei, deg);
    k_bsum<<<NBLK, 256, 0, stream>>>(deg, bsum);
    k_bscan<<<1, 512, 0, stream>>>(bsum, boff);
    k_off<<<NBLK, 256, 0, stream>>>(deg, boff, off, cursor);
    k_scatter<<<EB, 256, 0, stream>>>(ei, cursor, srt);

    k_gemm1<<<(N_NODESC + 63) / 64, 256, 0, stream>>>(x, W1, xw1);
    k_al1<<<(N_NODESC * H1C + 255) / 256, 256, 0, stream>>>(xw1, a1s, a1d, al1s, al1d);
    k_gat1<<<N_NODESC / 4, 256, 0, stream>>>(off, srt, al1s, al1d, xw1, b1, hmid);
    k_mid2<<<(N_NODESC + 255) / 256, 256, 0, stream>>>(hmid, W2, a2s, a2d, xw2, al2s, al2d);
    k_gat2<<<N_NODESC / 4, 256, 0, stream>>>(off, srt, al2s, al2d, xw2, b2, out);
}

// Round 4
// 765.970 us; speedup vs baseline: 1.5132x; 1.0027x over previous
//
#include <hip/hip_runtime.h>
#include <math.h>

#define N_NODESC 100000
#define N_EDGESC 1600000
#define E_TOT    1700000   // incl. self loops
#define IN_CH    500
#define KPAD     512
#define D1 64
#define H1C 8
#define D2 24
#define H2C 8
#define NBLK 391           // ceil(N_NODESC/256)

typedef __attribute__((ext_vector_type(8))) short short8;
typedef __attribute__((ext_vector_type(4))) float f32x4;

__device__ inline short f2bf(float f) {            // RTNE fp32 -> bf16
    unsigned u = __float_as_uint(f);
    u += 0x7fffu + ((u >> 16) & 1u);
    return (short)(u >> 16);
}

// ================= edge sort (counting sort by dst) =================
__global__ __launch_bounds__(256) void k_hist(const int* __restrict__ ei,
                                              int* __restrict__ deg) {
    const int e = blockIdx.x * 256 + threadIdx.x;
    if (e >= E_TOT) return;
    const int d = (e < N_EDGESC) ? ei[N_EDGESC + e] : (e - N_EDGESC);
    atomicAdd(deg + d, 1);
}

__global__ __launch_bounds__(256) void k_bsum(const int* __restrict__ deg,
                                              int* __restrict__ bsum) {
    const int i = blockIdx.x * 256 + threadIdx.x;
    int v = (i < N_NODESC) ? deg[i] : 0;
#pragma unroll
    for (int m = 1; m < 64; m <<= 1) v += __shfl_xor(v, m, 64);
    __shared__ int ws[4];
    if ((threadIdx.x & 63) == 0) ws[threadIdx.x >> 6] = v;
    __syncthreads();
    if (threadIdx.x == 0) bsum[blockIdx.x] = ws[0] + ws[1] + ws[2] + ws[3];
}

__global__ __launch_bounds__(512) void k_bscan(const int* __restrict__ bsum,
                                               int* __restrict__ boff) {
    __shared__ int sm[512];
    const int t = threadIdx.x;
    const int v = (t < NBLK) ? bsum[t] : 0;
    sm[t] = v;
    __syncthreads();
    for (int d = 1; d < 512; d <<= 1) {
        int u = (t >= d) ? sm[t - d] : 0;
        __syncthreads();
        sm[t] += u;
        __syncthreads();
    }
    if (t < NBLK) boff[t] = sm[t] - v;   // exclusive
}

__global__ __launch_bounds__(256) void k_off(const int* __restrict__ deg,
                                             const int* __restrict__ boff,
                                             int* __restrict__ off,
                                             int* __restrict__ cursor) {
    __shared__ int sm[256];
    const int t = threadIdx.x;
    const int i = blockIdx.x * 256 + t;
    const int v = (i < N_NODESC) ? deg[i] : 0;
    sm[t] = v;
    __syncthreads();
    for (int d = 1; d < 256; d <<= 1) {
        int u = (t >= d) ? sm[t - d] : 0;
        __syncthreads();
        sm[t] += u;
        __syncthreads();
    }
    if (i < N_NODESC) {
        const int ex = boff[blockIdx.x] + sm[t] - v;
        off[i] = ex;
        cursor[i] = ex;
    }
    if (i == 0) off[N_NODESC] = E_TOT;
}

__global__ __launch_bounds__(256) void k_scatter(const int* __restrict__ ei,
                                                 int* __restrict__ cursor,
                                                 int* __restrict__ srt_src) {
    const int e = blockIdx.x * 256 + threadIdx.x;
    if (e >= E_TOT) return;
    int s, d;
    if (e < N_EDGESC) { s = ei[e]; d = ei[N_EDGESC + e]; }
    else { s = d = e - N_EDGESC; }
    const int pos = atomicAdd(cursor + d, 1);
    srt_src[pos] = s;
}

// ================= W1 -> bf16 transposed, K zero-padded to 512 =================
// wT[n][k], k-contiguous, stride KPAD halfs.
__global__ __launch_bounds__(256) void k_wprep(const float* __restrict__ W1,
                                               short* __restrict__ wT) {
    const int idx = blockIdx.x * 256 + threadIdx.x;   // 64*512 = 32768
    if (idx >= D1 * KPAD) return;
    const int n = idx >> 9, k = idx & (KPAD - 1);
    wT[idx] = (k < IN_CH) ? f2bf(W1[k * D1 + n]) : (short)0;
}

// ================= K1: xw1 = x @ W1 via bf16 MFMA =================
// block: 256 thr = 4 waves, 128 rows. wave: 32 rows x 64 cols (2 m-frags x 4 n-frags).
// xs: bf16 [128 rows][32 k], row stride 40 halfs (80 B) -> 16B-aligned b128 A-frag reads,
//     bank pattern 20*row mod 32 -> 2-way (free).
__global__ __launch_bounds__(256) void k_gemm1(const float* __restrict__ x,
                                               const short* __restrict__ wT,
                                               float* __restrict__ xw1) {
    __shared__ short xs[128 * 40];
    const int t = threadIdx.x;
    const int rowBase = blockIdx.x * 128;
    const int wv = t >> 6, lane = t & 63;
    const int m = lane & 15, kg = lane >> 4;
    const int sr = t >> 1;                 // staging row 0..127
    const int sh = (t & 1) * 16;           // staging k-half

    f32x4 acc[2][4];
#pragma unroll
    for (int mf = 0; mf < 2; mf++)
#pragma unroll
        for (int nt = 0; nt < 4; nt++) acc[mf][nt] = (f32x4){0.f, 0.f, 0.f, 0.f};

    const int grow = rowBase + sr;
    for (int k0 = 0; k0 < KPAD; k0 += 32) {
        // ---- stage x tile as bf16 ----
        float4 v[4];
#pragma unroll
        for (int i = 0; i < 4; i++) {
            const int k = k0 + sh + i * 4;
            v[i] = (grow < N_NODESC && k < IN_CH)
                       ? *(const float4*)(x + (long)grow * IN_CH + k)
                       : make_float4(0.f, 0.f, 0.f, 0.f);
        }
        short8 p0, p1;
        p0[0]=f2bf(v[0].x); p0[1]=f2bf(v[0].y); p0[2]=f2bf(v[0].z); p0[3]=f2bf(v[0].w);
        p0[4]=f2bf(v[1].x); p0[5]=f2bf(v[1].y); p0[6]=f2bf(v[1].z); p0[7]=f2bf(v[1].w);
        p1[0]=f2bf(v[2].x); p1[1]=f2bf(v[2].y); p1[2]=f2bf(v[2].z); p1[3]=f2bf(v[2].w);
        p1[4]=f2bf(v[3].x); p1[5]=f2bf(v[3].y); p1[6]=f2bf(v[3].z); p1[7]=f2bf(v[3].w);
        __syncthreads();   // protect prev-iter reads
        *(short8*)(xs + sr * 40 + sh) = p0;
        *(short8*)(xs + sr * 40 + sh + 8) = p1;
        __syncthreads();

        // ---- B frags straight from global (L2-resident 64 KB) ----
        short8 bf[4];
#pragma unroll
        for (int nt = 0; nt < 4; nt++)
            bf[nt] = *(const short8*)(wT + (nt * 16 + m) * KPAD + k0 + kg * 8);
        short8 af[2];
#pragma unroll
        for (int mf = 0; mf < 2; mf++)
            af[mf] = *(const short8*)(xs + (wv * 32 + mf * 16 + m) * 40 + kg * 8);
#pragma unroll
        for (int mf = 0; mf < 2; mf++)
#pragma unroll
            for (int nt = 0; nt < 4; nt++)
                acc[mf][nt] = __builtin_amdgcn_mfma_f32_16x16x32_bf16(
                    af[mf], bf[nt], acc[mf][nt], 0, 0, 0);
    }

    // ---- epilogue: C layout row=(lane>>4)*4+reg, col=lane&15 ----
#pragma unroll
    for (int mf = 0; mf < 2; mf++) {
#pragma unroll
        for (int j = 0; j < 4; j++) {
            const int row = rowBase + wv * 32 + mf * 16 + kg * 4 + j;
            if (row < N_NODESC) {
#pragma unroll
                for (int nt = 0; nt < 4; nt++)
                    xw1[(long)row * D1 + nt * 16 + m] = acc[mf][nt][j];
            }
        }
    }
}

// ================= K2: attention logit projections, layer 1 =================
__global__ __launch_bounds__(256) void k_al1(const float* __restrict__ xw1,
                                             const float* __restrict__ a1s,
                                             const float* __restrict__ a1d,
                                             float* __restrict__ al1s,
                                             float* __restrict__ al1d) {
    const int gid = blockIdx.x * 256 + threadIdx.x;
    if (gid >= N_NODESC * H1C) return;
    const int n = gid >> 3, h = gid & 7;
    const float4* p = (const float4*)(xw1 + (long)n * D1 + h * 8);
    const float4 v0 = p[0], v1 = p[1];
    const float4* as = (const float4*)(a1s + h * 8);
    const float4 s0 = as[0], s1 = as[1];
    const float4* ad = (const float4*)(a1d + h * 8);
    const float4 d0 = ad[0], d1 = ad[1];
    al1s[gid] = v0.x * s0.x + v0.y * s0.y + v0.z * s0.z + v0.w * s0.w +
                v1.x * s1.x + v1.y * s1.y + v1.z * s1.z + v1.w * s1.w;
    al1d[gid] = v0.x * d0.x + v0.y * d0.y + v0.z * d0.z + v0.w * d0.w +
                v1.x * d1.x + v1.y * d1.y + v1.z * d1.z + v1.w * d1.w;
}

// ================= K3: gather-aggregate layer 1 =================
__global__ __launch_bounds__(256) void k_gat1(const int* __restrict__ off,
                                              const int* __restrict__ srt_src,
                                              const float* __restrict__ al1s,
                                              const float* __restrict__ al1d,
                                              const float* __restrict__ xw1,
                                              const float* __restrict__ b1,
                                              float* __restrict__ hmid) {
    const int tid = threadIdx.x;
    const int lane = tid & 63;
    const int wid = tid >> 6;
    const int n = blockIdx.x * 4 + wid;   // N_NODESC % 4 == 0
    const int esub = lane >> 4;
    const int q = lane & 15;
    const int h = q >> 1;

    const float ald = al1d[n * 8 + h];
    const int kend = off[n + 1];

    float4 acc = make_float4(0.f, 0.f, 0.f, 0.f);
    float ssum = 0.f;
    for (int k = off[n] + esub; k < kend; k += 4) {
        const int s = srt_src[k];
        float ev = al1s[s * 8 + h] + ald;
        ev = ev > 0.f ? ev : 0.2f * ev;
        const float ex = expf(ev);
        const float4 v = *(const float4*)(xw1 + (long)s * D1 + q * 4);
        acc.x += ex * v.x; acc.y += ex * v.y; acc.z += ex * v.z; acc.w += ex * v.w;
        ssum += ex;
    }
#pragma unroll
    for (int m = 16; m < 64; m <<= 1) {
        acc.x += __shfl_xor(acc.x, m, 64);
        acc.y += __shfl_xor(acc.y, m, 64);
        acc.z += __shfl_xor(acc.z, m, 64);
        acc.w += __shfl_xor(acc.w, m, 64);
        ssum  += __shfl_xor(ssum,  m, 64);
    }
    if (esub == 0) {
        const float inv = 1.0f / (ssum + 1e-16f);
        const float4 bb = *(const float4*)(b1 + q * 4);
        float4 r;
        r.x = acc.x * inv + bb.x; r.x = r.x > 0.f ? r.x : expm1f(r.x);
        r.y = acc.y * inv + bb.y; r.y = r.y > 0.f ? r.y : expm1f(r.y);
        r.z = acc.z * inv + bb.z; r.z = r.z > 0.f ? r.z : expm1f(r.z);
        r.w = acc.w * inv + bb.w; r.w = r.w > 0.f ? r.w : expm1f(r.w);
        *(float4*)(hmid + (long)n * D1 + q * 4) = r;
    }
}

// ================= K4: xw2 = hmid @ W2, al2 projections =================
__global__ __launch_bounds__(256) void k_mid2(const float* __restrict__ hmid,
                                              const float* __restrict__ W2,
                                              const float* __restrict__ a2s,
                                              const float* __restrict__ a2d,
                                              float* __restrict__ xw2,
                                              float* __restrict__ al2s,
                                              float* __restrict__ al2d) {
    __shared__ float w2s[D1 * D2];
    for (int i = threadIdx.x; i < D1 * D2; i += 256) w2s[i] = W2[i];
    __syncthreads();
    const int n = blockIdx.x * 256 + threadIdx.x;
    if (n >= N_NODESC) return;

    float o[D2];
#pragma unroll
    for (int j = 0; j < D2; j++) o[j] = 0.f;
#pragma unroll
    for (int c4 = 0; c4 < D1; c4 += 4) {
        const float4 hv = *(const float4*)(hmid + (long)n * D1 + c4);
        const float* wr = w2s + c4 * D2;
#pragma unroll
        for (int j = 0; j < D2; j++) {
            o[j] += hv.x * wr[j] + hv.y * wr[D2 + j] + hv.z * wr[2 * D2 + j] + hv.w * wr[3 * D2 + j];
        }
    }
#pragma unroll
    for (int j = 0; j < D2; j++) xw2[(long)n * D2 + j] = o[j];
#pragma unroll
    for (int hh = 0; hh < 8; hh++) {
        al2s[n * 8 + hh] = o[hh * 3] * a2s[hh * 3] + o[hh * 3 + 1] * a2s[hh * 3 + 1] + o[hh * 3 + 2] * a2s[hh * 3 + 2];
        al2d[n * 8 + hh] = o[hh * 3] * a2d[hh * 3] + o[hh * 3 + 1] * a2d[hh * 3 + 1] + o[hh * 3 + 2] * a2d[hh * 3 + 2];
    }
}

// ================= K5: gather-aggregate layer 2 + head-mean + softmax =================
__global__ __launch_bounds__(256) void k_gat2(const int* __restrict__ off,
                                              const int* __restrict__ srt_src,
                                              const float* __restrict__ al2s,
                                              const float* __restrict__ al2d,
                                              const float* __restrict__ xw2,
                                              const float* __restrict__ b2,
                                              float* __restrict__ out) {
    __shared__ float sm[4][24];
    const int tid = threadIdx.x;
    const int lane = tid & 63;
    const int wid = tid >> 6;
    const int n = blockIdx.x * 4 + wid;
    const int esub = lane / 24;          // 0,1,2
    const int j = lane - esub * 24;
    const int h = j / 3;

    float acc = 0.f, ssum = 0.f;
    if (esub < 2) {
        const float ald = al2d[n * 8 + h];
        const int kend = off[n + 1];
        for (int k = off[n] + esub; k < kend; k += 2) {
            const int s = srt_src[k];
            float ev = al2s[s * 8 + h] + ald;
            ev = ev > 0.f ? ev : 0.2f * ev;
            const float ex = expf(ev);
            acc += ex * xw2[(long)s * D2 + j];
            ssum += ex;
        }
    }
    acc  += __shfl_down(acc, 24, 64);
    ssum += __shfl_down(ssum, 24, 64);
    if (lane < 24) sm[wid][j] = acc / (ssum + 1e-16f);
    __syncthreads();
    float lg = 0.f;
    if (lane < 3) {
#pragma unroll
        for (int hh = 0; hh < 8; hh++) lg += sm[wid][hh * 3 + lane];
        lg = lg * 0.125f + b2[lane];
    }
    const float l0 = __shfl(lg, 0, 64);
    const float l1 = __shfl(lg, 1, 64);
    const float l2 = __shfl(lg, 2, 64);
    if (lane < 3) {
        const float m = fmaxf(l0, fmaxf(l1, l2));
        const float denom = expf(l0 - m) + expf(l1 - m) + expf(l2 - m);
        out[(long)n * 3 + lane] = expf(lg - m) / denom;
    }
}

extern "C" void kernel_launch(void* const* d_in, const int* in_sizes, int n_in,
                              void* d_out, int out_size, void* d_ws, size_t ws_size,
                              hipStream_t stream) {
    const float* x   = (const float*)d_in[0];
    const float* W1  = (const float*)d_in[1];
    const float* a1s = (const float*)d_in[2];
    const float* a1d = (const float*)d_in[3];
    const float* b1  = (const float*)d_in[4];
    const float* W2  = (const float*)d_in[5];
    const float* a2s = (const float*)d_in[6];
    const float* a2d = (const float*)d_in[7];
    const float* b2  = (const float*)d_in[8];
    const int*   ei  = (const int*)d_in[9];
    float* out = (float*)d_out;

    float* ws   = (float*)d_ws;
    float* xw1  = ws;                  // 6,400,000
    float* al1s = xw1  + 6400000;      //   800,000
    float* al1d = al1s + 800000;       //   800,000
    float* hmid = al1d + 800000;       // 6,400,000
    float* xw2  = hmid + 6400000;      // 2,400,000
    float* al2s = xw2  + 2400000;      //   800,000
    float* al2d = al2s + 800000;       //   800,000
    int* deg    = (int*)(al2d + 800000);   //   100,000
    int* off    = deg + 100000;            //   100,001
    int* cursor = off + 100001;            //   100,000
    int* srt    = cursor + 100000;         // 1,700,000
    int* bsum   = srt + 1700000;           //   NBLK
    int* boff   = bsum + NBLK;             //   NBLK
    short* wT   = (short*)(boff + NBLK);   //   64*512 halfs

    hipMemsetAsync(deg, 0, (size_t)N_NODESC * sizeof(int), stream);

    const int EB = (E_TOT + 255) / 256;
    k_hist<<<EB, 256, 0, stream>>>(ei, deg);
    k_bsum<<<NBLK, 256, 0, stream>>>(deg, bsum);
    k_bscan<<<1, 512, 0, stream>>>(bsum, boff);
    k_off<<<NBLK, 256, 0, stream>>>(deg, boff, off, cursor);
    k_scatter<<<EB, 256, 0, stream>>>(ei, cursor, srt);

    k_wprep<<<(D1 * KPAD + 255) / 256, 256, 0, stream>>>(W1, wT);
    k_gemm1<<<(N_NODESC + 127) / 128, 256, 0, stream>>>(x, wT, xw1);
    k_al1<<<(N_NODESC * H1C + 255) / 256, 256, 0, stream>>>(xw1, a1s, a1d, al1s, al1d);
    k_gat1<<<N_NODESC / 4, 256, 0, stream>>>(off, srt, al1s, al1d, xw1, b1, hmid);
    k_mid2<<<(N_NODESC + 255) / 256, 256, 0, stream>>>(hmid, W2, a2s, a2d, xw2, al2s, al2d);
    k_gat2<<<N_NODESC / 4, 256, 0, stream>>>(off, srt, al2s, al2d, xw2, b2, out);
}